// Round 1
// baseline (253.280 us; speedup 1.0000x reference)
//
#include <hip/hip_runtime.h>
#include <hip/hip_bf16.h>

#define B_ 8192
#define I_ 512
#define H_ 1024
#define R_ 64

typedef __bf16 bf16x8 __attribute__((ext_vector_type(8)));
typedef short  s16x8  __attribute__((ext_vector_type(8)));
typedef float  f32x4  __attribute__((ext_vector_type(4)));

static __device__ __forceinline__ short f2bf(float f) {
    union { float f; unsigned u; } v; v.f = f;
    unsigned r = v.u + 0x7fffu + ((v.u >> 16) & 1u);
    return (short)(r >> 16);
}

static __device__ __forceinline__ float sigmoidf_(float v) {
    return 1.f / (1.f + __expf(-v));
}
static __device__ __forceinline__ float tanhf_(float v) {
    return 2.f / (1.f + __expf(-2.f * v)) - 1.f;
}

// ---------------------------------------------------------------------------
// Prep: u_xT[64][512] bf16, u_hT[64][1024] bf16, Vc[4096][128] bf16 (v_x|v_h),
// coef_x[4][512] f32, coef_h[4][1024] f32.
// ---------------------------------------------------------------------------
__global__ __launch_bounds__(256) void prep_kernel(
    const float* __restrict__ u_x, const float* __restrict__ u_h,
    const float* __restrict__ v_x, const float* __restrict__ v_h,
    short* __restrict__ uxT, short* __restrict__ uhT, short* __restrict__ Vc,
    float* __restrict__ coef_x, float* __restrict__ coef_h)
{
    int t = blockIdx.x * 256 + threadIdx.x;
    // u_xT: 64*512
    if (t < 64 * 512) {
        int r = t / 512, k = t % 512;
        uxT[t] = f2bf(u_x[k * 64 + r]);
        return;
    }
    t -= 64 * 512;
    // u_hT: 64*1024
    if (t < 64 * 1024) {
        int r = t / 1024, k = t % 1024;
        uhT[t] = f2bf(u_h[k * 64 + r]);
        return;
    }
    t -= 64 * 1024;
    // Vc: 4096*128
    if (t < 4096 * 128) {
        int n = t >> 7, q = t & 127;
        Vc[t] = f2bf(q < 64 ? v_x[n * 64 + q] : v_h[n * 64 + (q - 64)]);
        return;
    }
    t -= 4096 * 128;
    // coef_x: 4*512 dots over R=64
    if (t < 4 * 512) {
        int g = t / 512, j = t % 512;
        float s = 0.f;
        for (int r = 0; r < 64; ++r)
            s += u_x[j * 64 + r] * v_x[(g * H_ + j) * 64 + r];
        coef_x[t] = s;
        return;
    }
    t -= 4 * 512;
    // coef_h: 4*1024 dots over R=64
    if (t < 4 * 1024) {
        int g = t >> 10, j = t & 1023;
        float s = 0.f;
        for (int r = 0; r < 64; ++r)
            s += u_h[j * 64 + r] * v_h[(g * H_ + j) * 64 + r];
        coef_h[t] = s;
        return;
    }
}

// ---------------------------------------------------------------------------
// Stage 1: P[b][0:64] = x @ u_x, P[b][64:128] = h @ u_h  (bf16 MFMA)
// blockIdx.y selects which sub-GEMM. Block = 4 waves, each wave = 16 rows x 64 cols.
// ---------------------------------------------------------------------------
__global__ __launch_bounds__(256) void stage1_kernel(
    const float* __restrict__ x, const float* __restrict__ h,
    const short* __restrict__ uxT, const short* __restrict__ uhT,
    short* __restrict__ P)
{
    const int w = threadIdx.x >> 6, lane = threadIdx.x & 63;
    const int quad = lane >> 4, lr = lane & 15;

    const float* X; const short* UT; int K, co;
    if (blockIdx.y == 0) { X = x; UT = uxT; K = I_; co = 0; }
    else                 { X = h; UT = uhT; K = H_; co = 64; }

    const int b0 = blockIdx.x * 64 + w * 16;

    f32x4 acc[4] = {};
    const float* ap = X + (size_t)(b0 + lr) * K + quad * 8;

    for (int k0 = 0; k0 < K; k0 += 32) {
        float4 alo = *(const float4*)(ap + k0);
        float4 ahi = *(const float4*)(ap + k0 + 4);
        s16x8 as;
        as[0] = f2bf(alo.x); as[1] = f2bf(alo.y);
        as[2] = f2bf(alo.z); as[3] = f2bf(alo.w);
        as[4] = f2bf(ahi.x); as[5] = f2bf(ahi.y);
        as[6] = f2bf(ahi.z); as[7] = f2bf(ahi.w);
        bf16x8 af = __builtin_bit_cast(bf16x8, as);
#pragma unroll
        for (int nt = 0; nt < 4; ++nt) {
            bf16x8 bf = *(const bf16x8*)(UT + (size_t)(nt * 16 + lr) * K + k0 + quad * 8);
            acc[nt] = __builtin_amdgcn_mfma_f32_16x16x32_bf16(af, bf, acc[nt], 0, 0, 0);
        }
    }

#pragma unroll
    for (int nt = 0; nt < 4; ++nt)
#pragma unroll
        for (int r = 0; r < 4; ++r) {
            int row = b0 + quad * 4 + r;
            P[(size_t)row * 128 + co + nt * 16 + lr] = f2bf(acc[nt][r]);
        }
}

// ---------------------------------------------------------------------------
// Stage 2: gates = P @ Vc^T (M=8192, N=4H, K=128) with fused LSTM epilogue.
// Block = 4 waves; wave = 64 rows x 16 j-cols x 4 gate tiles.
// Lane holds all 4 gates of each (b,j) -> epilogue fully in-register.
// ---------------------------------------------------------------------------
__global__ __launch_bounds__(256) void stage2_kernel(
    const short* __restrict__ P, const short* __restrict__ Vc,
    const float* __restrict__ x, const float* __restrict__ h,
    const float* __restrict__ c,
    const float* __restrict__ coef_x, const float* __restrict__ coef_h,
    const float* __restrict__ b_x, const float* __restrict__ b_h,
    const float* __restrict__ dia_x, const float* __restrict__ dia_h,
    float* __restrict__ out)
{
    const int w = threadIdx.x >> 6, lane = threadIdx.x & 63;
    const int quad = lane >> 4, lr = lane & 15;
    const int b0 = blockIdx.x * 64;
    const int j0 = blockIdx.y * 64 + w * 16;
    const int j = j0 + lr;

    f32x4 acc[4][4] = {};

#pragma unroll
    for (int ks = 0; ks < 4; ++ks) {
        const int k0 = ks * 32 + quad * 8;
        bf16x8 a[4], b[4];
#pragma unroll
        for (int mt = 0; mt < 4; ++mt)
            a[mt] = *(const bf16x8*)(P + (size_t)(b0 + mt * 16 + lr) * 128 + k0);
#pragma unroll
        for (int g = 0; g < 4; ++g)
            b[g] = *(const bf16x8*)(Vc + (size_t)(g * H_ + j0 + lr) * 128 + k0);
#pragma unroll
        for (int mt = 0; mt < 4; ++mt)
#pragma unroll
            for (int g = 0; g < 4; ++g)
                acc[mt][g] = __builtin_amdgcn_mfma_f32_16x16x32_bf16(a[mt], b[g], acc[mt][g], 0, 0, 0);
    }

    // per-j (lane-constant) epilogue inputs
    const bool jx = (j < I_);
    const float dx = jx ? dia_x[j] : 0.f;
    const float dh = dia_h[j];
    float cx[4], ch[4], bsum[4];
#pragma unroll
    for (int g = 0; g < 4; ++g) {
        cx[g]   = jx ? coef_x[g * I_ + j] : 0.f;
        ch[g]   = coef_h[g * H_ + j];
        bsum[g] = b_x[g * H_ + j] + b_h[g * H_ + j];
    }

#pragma unroll
    for (int mt = 0; mt < 4; ++mt) {
#pragma unroll
        for (int r = 0; r < 4; ++r) {
            const int brow = b0 + mt * 16 + quad * 4 + r;
            const float xv = jx ? x[(size_t)brow * I_ + j] : 0.f;
            const float hv = h[(size_t)brow * H_ + j];
            const float cv = c[(size_t)brow * H_ + j];
            const float z  = dx * xv + dh * hv;

            const float g0 = acc[mt][0][r] - xv * cx[0] - hv * ch[0] + bsum[0] + z;
            const float g1 = acc[mt][1][r] - xv * cx[1] - hv * ch[1] + bsum[1] + z;
            const float g2 = acc[mt][2][r] - xv * cx[2] - hv * ch[2] + bsum[2] + z;
            const float g3 = acc[mt][3][r] - xv * cx[3] - hv * ch[3] + bsum[3] + z;

            const float ig = sigmoidf_(g0);
            const float fg = sigmoidf_(g1);
            const float og = sigmoidf_(g2);
            const float ng = tanhf_(g3);

            const float cn = fg * cv + ig * ng;
            const float hn = og * tanhf_(cn);

            out[(size_t)brow * H_ + j] = hn;
            out[(size_t)B_ * H_ + (size_t)brow * H_ + j] = cn;
        }
    }
}

// ---------------------------------------------------------------------------
extern "C" void kernel_launch(void* const* d_in, const int* in_sizes, int n_in,
                              void* d_out, int out_size, void* d_ws, size_t ws_size,
                              hipStream_t stream) {
    const float* x     = (const float*)d_in[0];
    const float* h     = (const float*)d_in[1];
    const float* c     = (const float*)d_in[2];
    const float* u_x   = (const float*)d_in[3];
    const float* u_h   = (const float*)d_in[4];
    const float* v_x   = (const float*)d_in[5];
    const float* v_h   = (const float*)d_in[6];
    const float* b_x   = (const float*)d_in[7];
    const float* b_h   = (const float*)d_in[8];
    const float* dia_x = (const float*)d_in[9];
    const float* dia_h = (const float*)d_in[10];
    float* out = (float*)d_out;

    char* ws = (char*)d_ws;
    short* P      = (short*)(ws);                       // 8192*128*2   = 2,097,152
    short* uxT    = (short*)(ws + 2097152);             // 64*512*2     =    65,536
    short* uhT    = (short*)(ws + 2097152 + 65536);     // 64*1024*2    =   131,072
    short* Vc     = (short*)(ws + 2097152 + 65536 + 131072);        // 4096*128*2 = 1,048,576
    float* coef_x = (float*)(ws + 2097152 + 65536 + 131072 + 1048576);          // 4*512*4
    float* coef_h = (float*)(ws + 2097152 + 65536 + 131072 + 1048576 + 8192);   // 4*1024*4

    // prep: 32768 + 65536 + 524288 + 2048 + 4096 = 628736 threads
    prep_kernel<<<2456, 256, 0, stream>>>(u_x, u_h, v_x, v_h, uxT, uhT, Vc, coef_x, coef_h);
    stage1_kernel<<<dim3(128, 2), 256, 0, stream>>>(x, h, uxT, uhT, P);
    stage2_kernel<<<dim3(128, 16), 256, 0, stream>>>(P, Vc, x, h, c,
                                                     coef_x, coef_h, b_x, b_h,
                                                     dia_x, dia_h, out);
}

// Round 3
// 236.636 us; speedup vs baseline: 1.0703x; 1.0703x over previous
//
#include <hip/hip_runtime.h>
#include <hip/hip_bf16.h>

#define B_ 8192
#define I_ 512
#define H_ 1024
#define R_ 64

typedef __bf16 bf16x8 __attribute__((ext_vector_type(8)));
typedef short  s16x8  __attribute__((ext_vector_type(8)));
typedef float  f32x4  __attribute__((ext_vector_type(4)));

static __device__ __forceinline__ short f2bf(float f) {
    union { float f; unsigned u; } v; v.f = f;
    unsigned r = v.u + 0x7fffu + ((v.u >> 16) & 1u);
    return (short)(r >> 16);
}

static __device__ __forceinline__ float sigmoidf_(float v) {
    return 1.f / (1.f + __expf(-v));
}
static __device__ __forceinline__ float tanhf_(float v) {
    return 2.f / (1.f + __expf(-2.f * v)) - 1.f;
}

// ---------------------------------------------------------------------------
// Prep: u_xT[64][512] bf16, u_hT[64][1024] bf16, Vc[4096][128] bf16 (v_x|v_h),
// coef_x[4][512] f32, coef_h[4][1024] f32.
// ---------------------------------------------------------------------------
__global__ __launch_bounds__(256) void prep_kernel(
    const float* __restrict__ u_x, const float* __restrict__ u_h,
    const float* __restrict__ v_x, const float* __restrict__ v_h,
    short* __restrict__ uxT, short* __restrict__ uhT, short* __restrict__ Vc,
    float* __restrict__ coef_x, float* __restrict__ coef_h)
{
    int t = blockIdx.x * 256 + threadIdx.x;
    if (t < 64 * 512) {                       // u_xT
        int r = t / 512, k = t % 512;
        uxT[t] = f2bf(u_x[k * 64 + r]);
        return;
    }
    t -= 64 * 512;
    if (t < 64 * 1024) {                      // u_hT
        int r = t / 1024, k = t % 1024;
        uhT[t] = f2bf(u_h[k * 64 + r]);
        return;
    }
    t -= 64 * 1024;
    if (t < 4096 * 128) {                     // Vc
        int n = t >> 7, q = t & 127;
        Vc[t] = f2bf(q < 64 ? v_x[n * 64 + q] : v_h[n * 64 + (q - 64)]);
        return;
    }
    t -= 4096 * 128;
    if (t < 4 * 512) {                        // coef_x
        int g = t / 512, j = t % 512;
        float s = 0.f;
        for (int r = 0; r < 64; ++r)
            s += u_x[j * 64 + r] * v_x[(g * H_ + j) * 64 + r];
        coef_x[t] = s;
        return;
    }
    t -= 4 * 512;
    if (t < 4 * 1024) {                       // coef_h
        int g = t >> 10, j = t & 1023;
        float s = 0.f;
        for (int r = 0; r < 64; ++r)
            s += u_h[j * 64 + r] * v_h[(g * H_ + j) * 64 + r];
        coef_h[t] = s;
        return;
    }
}

// ---------------------------------------------------------------------------
// Stage 1: P[b][0:64] = x @ u_x, P[b][64:128] = h @ u_h  (bf16 MFMA)
// Wave tile = 16 rows x 16 cols (single acc chain) -> 4096 waves (~4/SIMD).
// Block = 4 waves covering 16 rows x 64 cols; A rows shared through L1.
// ---------------------------------------------------------------------------
__global__ __launch_bounds__(256) void stage1_kernel(
    const float* __restrict__ x, const float* __restrict__ h,
    const short* __restrict__ uxT, const short* __restrict__ uhT,
    short* __restrict__ P)
{
    const int w = threadIdx.x >> 6, lane = threadIdx.x & 63;
    const int quad = lane >> 4, lr = lane & 15;

    const float* X; const short* UT; int K, co;
    if (blockIdx.y == 0) { X = x; UT = uxT; K = I_; co = 0; }
    else                 { X = h; UT = uhT; K = H_; co = 64; }

    const int b0 = blockIdx.x * 16;   // 512 row-tiles
    const int n0 = w * 16;            // col tile within the 64-wide half

    f32x4 acc = {};
    const float* ap = X + (size_t)(b0 + lr) * K + quad * 8;
    const short* bp = UT + (size_t)(n0 + lr) * K + quad * 8;

    for (int k0 = 0; k0 < K; k0 += 32) {
        float4 alo = *(const float4*)(ap + k0);
        float4 ahi = *(const float4*)(ap + k0 + 4);
        s16x8 as;
        as[0] = f2bf(alo.x); as[1] = f2bf(alo.y);
        as[2] = f2bf(alo.z); as[3] = f2bf(alo.w);
        as[4] = f2bf(ahi.x); as[5] = f2bf(ahi.y);
        as[6] = f2bf(ahi.z); as[7] = f2bf(ahi.w);
        bf16x8 af = __builtin_bit_cast(bf16x8, as);
        bf16x8 bf = *(const bf16x8*)(bp + k0);
        acc = __builtin_amdgcn_mfma_f32_16x16x32_bf16(af, bf, acc, 0, 0, 0);
    }

#pragma unroll
    for (int r = 0; r < 4; ++r)
        P[(size_t)(b0 + quad * 4 + r) * 128 + co + n0 + lr] = f2bf(acc[r]);
}

// ---------------------------------------------------------------------------
// Stage 2: gates = P @ Vc^T (M=8192, N=4H, K=128) with fused LSTM epilogue.
// 64-thread blocks (1 wave, no sync needed). Wave = 64 rows x 16 j x 4 gates.
// Grid: (B/64, H/16) = (128, 64)  [the 4 gates are the in-kernel g loop].
// Epilogue operands (x/h/c) PREFETCHED before the MFMA loop so their HBM
// latency overlaps the compute phase.
// ---------------------------------------------------------------------------
__global__ __launch_bounds__(64) void stage2_kernel(
    const short* __restrict__ P, const short* __restrict__ Vc,
    const float* __restrict__ x, const float* __restrict__ h,
    const float* __restrict__ c,
    const float* __restrict__ coef_x, const float* __restrict__ coef_h,
    const float* __restrict__ b_x, const float* __restrict__ b_h,
    const float* __restrict__ dia_x, const float* __restrict__ dia_h,
    float* __restrict__ out)
{
    const int lane = threadIdx.x;
    const int quad = lane >> 4, lr = lane & 15;
    const int b0 = blockIdx.x * 64;
    const int j0 = blockIdx.y * 16;          // j0 in [0, H)
    const int j = j0 + lr;
    const bool jx = (j < I_);

    // ---- prefetch epilogue operands (independent of MFMA results) ----
    float cv[16], hv[16], xv[16];
#pragma unroll
    for (int mt = 0; mt < 4; ++mt)
#pragma unroll
        for (int r = 0; r < 4; ++r) {
            const int brow = b0 + mt * 16 + quad * 4 + r;
            cv[mt * 4 + r] = c[(size_t)brow * H_ + j];
            hv[mt * 4 + r] = h[(size_t)brow * H_ + j];
            xv[mt * 4 + r] = jx ? x[(size_t)brow * I_ + j] : 0.f;
        }

    // per-j (lane-constant) small operands — L1/L2 resident
    const float dx = jx ? dia_x[j] : 0.f;
    const float dh = dia_h[j];
    float cx[4], ch[4], bsum[4];
#pragma unroll
    for (int g = 0; g < 4; ++g) {
        cx[g]   = jx ? coef_x[g * I_ + j] : 0.f;
        ch[g]   = coef_h[g * H_ + j];
        bsum[g] = b_x[g * H_ + j] + b_h[g * H_ + j];
    }

    // ---- MFMA phase ----
    f32x4 acc[4][4] = {};
#pragma unroll
    for (int ks = 0; ks < 4; ++ks) {
        const int k0 = ks * 32 + quad * 8;
        bf16x8 a[4], b[4];
#pragma unroll
        for (int mt = 0; mt < 4; ++mt)
            a[mt] = *(const bf16x8*)(P + (size_t)(b0 + mt * 16 + lr) * 128 + k0);
#pragma unroll
        for (int g = 0; g < 4; ++g)
            b[g] = *(const bf16x8*)(Vc + (size_t)(g * H_ + j0 + lr) * 128 + k0);
#pragma unroll
        for (int mt = 0; mt < 4; ++mt)
#pragma unroll
            for (int g = 0; g < 4; ++g)
                acc[mt][g] = __builtin_amdgcn_mfma_f32_16x16x32_bf16(a[mt], b[g], acc[mt][g], 0, 0, 0);
    }

    // ---- epilogue (all operands already in registers) ----
#pragma unroll
    for (int mt = 0; mt < 4; ++mt) {
#pragma unroll
        for (int r = 0; r < 4; ++r) {
            const int brow = b0 + mt * 16 + quad * 4 + r;
            const int e = mt * 4 + r;
            const float xe = xv[e], he = hv[e];
            const float z  = dx * xe + dh * he;

            const float g0 = acc[mt][0][r] - xe * cx[0] - he * ch[0] + bsum[0] + z;
            const float g1 = acc[mt][1][r] - xe * cx[1] - he * ch[1] + bsum[1] + z;
            const float g2 = acc[mt][2][r] - xe * cx[2] - he * ch[2] + bsum[2] + z;
            const float g3 = acc[mt][3][r] - xe * cx[3] - he * ch[3] + bsum[3] + z;

            const float ig = sigmoidf_(g0);
            const float fg = sigmoidf_(g1);
            const float og = sigmoidf_(g2);
            const float ng = tanhf_(g3);

            const float cn = fg * cv[e] + ig * ng;
            const float hn = og * tanhf_(cn);

            out[(size_t)brow * H_ + j] = hn;
            out[(size_t)B_ * H_ + (size_t)brow * H_ + j] = cn;
        }
    }
}

// ---------------------------------------------------------------------------
extern "C" void kernel_launch(void* const* d_in, const int* in_sizes, int n_in,
                              void* d_out, int out_size, void* d_ws, size_t ws_size,
                              hipStream_t stream) {
    const float* x     = (const float*)d_in[0];
    const float* h     = (const float*)d_in[1];
    const float* c     = (const float*)d_in[2];
    const float* u_x   = (const float*)d_in[3];
    const float* u_h   = (const float*)d_in[4];
    const float* v_x   = (const float*)d_in[5];
    const float* v_h   = (const float*)d_in[6];
    const float* b_x   = (const float*)d_in[7];
    const float* b_h   = (const float*)d_in[8];
    const float* dia_x = (const float*)d_in[9];
    const float* dia_h = (const float*)d_in[10];
    float* out = (float*)d_out;

    char* ws = (char*)d_ws;
    short* P      = (short*)(ws);                                    // 2,097,152 B
    short* uxT    = (short*)(ws + 2097152);                          //    65,536
    short* uhT    = (short*)(ws + 2097152 + 65536);                  //   131,072
    short* Vc     = (short*)(ws + 2097152 + 65536 + 131072);         // 1,048,576
    float* coef_x = (float*)(ws + 2097152 + 65536 + 131072 + 1048576);
    float* coef_h = (float*)(ws + 2097152 + 65536 + 131072 + 1048576 + 8192);

    prep_kernel<<<2456, 256, 0, stream>>>(u_x, u_h, v_x, v_h, uxT, uhT, Vc, coef_x, coef_h);
    stage1_kernel<<<dim3(512, 2), 256, 0, stream>>>(x, h, uxT, uhT, P);
    // Grid y = H/16 = 64 (NOT 4H/16: the 4 gates are the in-kernel g loop).
    stage2_kernel<<<dim3(128, 64), 64, 0, stream>>>(P, Vc, x, h, c,
                                                    coef_x, coef_h, b_x, b_h,
                                                    dia_x, dia_h, out);
}

// Round 4
// 200.637 us; speedup vs baseline: 1.2624x; 1.1794x over previous
//
#include <hip/hip_runtime.h>
#include <hip/hip_bf16.h>

#define B_ 8192
#define I_ 512
#define H_ 1024
#define R_ 64

typedef __bf16 bf16x8 __attribute__((ext_vector_type(8)));
typedef short  s16x8  __attribute__((ext_vector_type(8)));
typedef float  f32x4  __attribute__((ext_vector_type(4)));

static __device__ __forceinline__ short f2bf(float f) {
    union { float f; unsigned u; } v; v.f = f;
    unsigned r = v.u + 0x7fffu + ((v.u >> 16) & 1u);
    return (short)(r >> 16);
}

static __device__ __forceinline__ float sigmoidf_(float v) {
    return 1.f / (1.f + __expf(-v));
}
static __device__ __forceinline__ float tanhf_(float v) {
    return 2.f / (1.f + __expf(-2.f * v)) - 1.f;
}

// ---------------------------------------------------------------------------
// Prep: u_xT[64][512] bf16, u_hT[64][1024] bf16, Vc[4096][128] bf16 (v_x|v_h),
// coef_x[4][512] f32, coef_h[4][1024] f32.
// Transposes: coalesced READS (scattered 2B writes; arrays are tiny).
// ---------------------------------------------------------------------------
__global__ __launch_bounds__(256) void prep_kernel(
    const float* __restrict__ u_x, const float* __restrict__ u_h,
    const float* __restrict__ v_x, const float* __restrict__ v_h,
    short* __restrict__ uxT, short* __restrict__ uhT, short* __restrict__ Vc,
    float* __restrict__ coef_x, float* __restrict__ coef_h)
{
    int t = blockIdx.x * 256 + threadIdx.x;
    if (t < 64 * 512) {                       // uxT[r][k] = u_x[k][r]
        int k = t >> 6, r = t & 63;
        uxT[r * 512 + k] = f2bf(u_x[t]);      // read coalesced
        return;
    }
    t -= 64 * 512;
    if (t < 64 * 1024) {                      // uhT[r][k] = u_h[k][r]
        int k = t >> 6, r = t & 63;
        uhT[r * 1024 + k] = f2bf(u_h[t]);
        return;
    }
    t -= 64 * 1024;
    if (t < 4096 * 128) {                     // Vc
        int n = t >> 7, q = t & 127;
        Vc[t] = f2bf(q < 64 ? v_x[n * 64 + q] : v_h[n * 64 + (q - 64)]);
        return;
    }
    t -= 4096 * 128;
    if (t < 4 * 512) {                        // coef_x
        int g = t / 512, j = t % 512;
        const float4* up = (const float4*)(u_x + (size_t)j * 64);
        const float4* vp = (const float4*)(v_x + (size_t)(g * H_ + j) * 64);
        float s = 0.f;
#pragma unroll
        for (int r = 0; r < 16; ++r) {
            float4 a = up[r], b = vp[r];
            s += a.x * b.x + a.y * b.y + a.z * b.z + a.w * b.w;
        }
        coef_x[t] = s;
        return;
    }
    t -= 4 * 512;
    if (t < 4 * 1024) {                       // coef_h
        int g = t >> 10, j = t & 1023;
        const float4* up = (const float4*)(u_h + (size_t)j * 64);
        const float4* vp = (const float4*)(v_h + (size_t)(g * H_ + j) * 64);
        float s = 0.f;
#pragma unroll
        for (int r = 0; r < 16; ++r) {
            float4 a = up[r], b = vp[r];
            s += a.x * b.x + a.y * b.y + a.z * b.z + a.w * b.w;
        }
        coef_h[t] = s;
        return;
    }
}

// ---------------------------------------------------------------------------
// Stage 1: P[b][0:64] = x @ u_x, P[b][64:128] = h @ u_h  (bf16 MFMA)
// 1024-thread blocks (16 waves), 64 batch rows per block, K-chunks of 128
// staged fp32->bf16 into LDS (coalesced). Wave w = (m-tile w>>2, n-tile w&3).
// Grid (B/64, 2): y=0 -> x-half (K=512), y=1 -> h-half (K=1024).
// ---------------------------------------------------------------------------
__global__ __launch_bounds__(1024) void stage1_kernel(
    const float* __restrict__ x, const float* __restrict__ h,
    const short* __restrict__ uxT, const short* __restrict__ uhT,
    short* __restrict__ P)
{
    __shared__ short At[64 * 136];   // 64 rows x 128-k chunk, pitch 136 (16B-aligned)
    const int w = threadIdx.x >> 6, lane = threadIdx.x & 63;
    const int quad = lane >> 4, lr = lane & 15;
    const int mt = w >> 2;            // m-tile 0..3
    const int n0 = (w & 3) * 16;      // n-tile col base 0..48

    const float* X; const short* UT; int K, co;
    if (blockIdx.y == 0) { X = x; UT = uxT; K = I_; co = 0; }
    else                 { X = h; UT = uhT; K = H_; co = 64; }

    const int b0 = blockIdx.x * 64;
    const int srow = threadIdx.x >> 4;          // 0..63
    const int scol = (threadIdx.x & 15) * 8;    // 0..120

    f32x4 acc = {};
    const short* bp = UT + (size_t)(n0 + lr) * K + quad * 8;
    const short* arow = At + (mt * 16 + lr) * 136 + quad * 8;

    for (int k0 = 0; k0 < K; k0 += 128) {
        // stage 64x128 fp32 -> bf16 into LDS (coalesced 32B per thread)
        const float* src = X + (size_t)(b0 + srow) * K + k0 + scol;
        float4 v0 = ((const float4*)src)[0];
        float4 v1 = ((const float4*)src)[1];
        s16x8 p;
        p[0] = f2bf(v0.x); p[1] = f2bf(v0.y); p[2] = f2bf(v0.z); p[3] = f2bf(v0.w);
        p[4] = f2bf(v1.x); p[5] = f2bf(v1.y); p[6] = f2bf(v1.z); p[7] = f2bf(v1.w);
        __syncthreads();               // previous chunk fully consumed
        *(s16x8*)(At + srow * 136 + scol) = p;
        __syncthreads();
#pragma unroll
        for (int ks = 0; ks < 4; ++ks) {
            bf16x8 bfrag = *(const bf16x8*)(bp + k0 + ks * 32);
            bf16x8 afrag = *(const bf16x8*)(arow + ks * 32);
            acc = __builtin_amdgcn_mfma_f32_16x16x32_bf16(afrag, bfrag, acc, 0, 0, 0);
        }
    }

#pragma unroll
    for (int r = 0; r < 4; ++r)
        P[(size_t)(b0 + mt * 16 + quad * 4 + r) * 128 + co + n0 + lr] = f2bf(acc[r]);
}

// ---------------------------------------------------------------------------
// Stage 2: gates = P @ Vc^T with fused LSTM epilogue.
// Block = 256 thr (4 waves) = 256 batch rows x 16 j.  Grid (B/256, H/16).
// Vc j-tile (4 gates x 16 j x 128 k, 17 KB) staged once into LDS, shared.
// Per wave: 4 m-tiles of 16 rows processed sequentially -> acc = 16 AGPRs,
// epi prefetch = 12 VGPRs (was 64+48) -> ~4 waves/SIMD occupancy.
// ---------------------------------------------------------------------------
__global__ __launch_bounds__(256) void stage2_kernel(
    const short* __restrict__ P, const short* __restrict__ Vc,
    const float* __restrict__ x, const float* __restrict__ h,
    const float* __restrict__ c,
    const float* __restrict__ coef_x, const float* __restrict__ coef_h,
    const float* __restrict__ b_x, const float* __restrict__ b_h,
    const float* __restrict__ dia_x, const float* __restrict__ dia_h,
    float* __restrict__ out)
{
    __shared__ short Bt[4 * 16 * 136];   // [gate][j-row][k], pitch 136
    const int w = threadIdx.x >> 6, lane = threadIdx.x & 63;
    const int quad = lane >> 4, lr = lane & 15;
    const int b0 = blockIdx.x * 256 + w * 64;
    const int j0 = blockIdx.y * 16;
    const int j = j0 + lr;
    const bool jx = (j < I_);

    // stage Vc tile: 64 rows (4 gates x 16 j) x 128 k, 64B per thread
    {
        const int row = threadIdx.x >> 2;          // 0..63
        const int g = row >> 4, jj = row & 15;
        const int col = (threadIdx.x & 3) * 32;    // elements
        const short* src = Vc + (size_t)(g * H_ + j0 + jj) * 128 + col;
        short* dst = Bt + (g * 16 + jj) * 136 + col;
        *(s16x8*)(dst)      = *(const s16x8*)(src);
        *(s16x8*)(dst + 8)  = *(const s16x8*)(src + 8);
        *(s16x8*)(dst + 16) = *(const s16x8*)(src + 16);
        *(s16x8*)(dst + 24) = *(const s16x8*)(src + 24);
    }

    // per-j (lane-constant) small operands — L1/L2 resident
    const float dx = jx ? dia_x[j] : 0.f;
    const float dh = dia_h[j];
    float cx[4], ch[4], bsum[4];
#pragma unroll
    for (int g = 0; g < 4; ++g) {
        cx[g]   = jx ? coef_x[g * I_ + j] : 0.f;
        ch[g]   = coef_h[g * H_ + j];
        bsum[g] = b_x[g * H_ + j] + b_h[g * H_ + j];
    }
    __syncthreads();

    for (int mt = 0; mt < 4; ++mt) {
        const int r0 = b0 + mt * 16;

        // epilogue prefetch for this m-tile (12 loads, overlap MFMA latency)
        float xv[4], hv[4], cv[4];
#pragma unroll
        for (int r = 0; r < 4; ++r) {
            const int brow = r0 + quad * 4 + r;
            cv[r] = c[(size_t)brow * H_ + j];
            hv[r] = h[(size_t)brow * H_ + j];
            xv[r] = jx ? x[(size_t)brow * I_ + j] : 0.f;
        }

        f32x4 acc[4] = {};
#pragma unroll
        for (int ks = 0; ks < 4; ++ks) {
            bf16x8 a = *(const bf16x8*)(P + (size_t)(r0 + lr) * 128 + ks * 32 + quad * 8);
#pragma unroll
            for (int g = 0; g < 4; ++g) {
                bf16x8 b = *(const bf16x8*)(Bt + (g * 16 + lr) * 136 + ks * 32 + quad * 8);
                acc[g] = __builtin_amdgcn_mfma_f32_16x16x32_bf16(a, b, acc[g], 0, 0, 0);
            }
        }

#pragma unroll
        for (int r = 0; r < 4; ++r) {
            const int brow = r0 + quad * 4 + r;
            const float xe = xv[r], he = hv[r];
            const float z  = dx * xe + dh * he;

            const float g0 = acc[0][r] - xe * cx[0] - he * ch[0] + bsum[0] + z;
            const float g1 = acc[1][r] - xe * cx[1] - he * ch[1] + bsum[1] + z;
            const float g2 = acc[2][r] - xe * cx[2] - he * ch[2] + bsum[2] + z;
            const float g3 = acc[3][r] - xe * cx[3] - he * ch[3] + bsum[3] + z;

            const float ig = sigmoidf_(g0);
            const float fg = sigmoidf_(g1);
            const float og = sigmoidf_(g2);
            const float ng = tanhf_(g3);

            const float cn = fg * cv[r] + ig * ng;
            const float hn = og * tanhf_(cn);

            out[(size_t)brow * H_ + j] = hn;
            out[(size_t)B_ * H_ + (size_t)brow * H_ + j] = cn;
        }
    }
}

// ---------------------------------------------------------------------------
extern "C" void kernel_launch(void* const* d_in, const int* in_sizes, int n_in,
                              void* d_out, int out_size, void* d_ws, size_t ws_size,
                              hipStream_t stream) {
    const float* x     = (const float*)d_in[0];
    const float* h     = (const float*)d_in[1];
    const float* c     = (const float*)d_in[2];
    const float* u_x   = (const float*)d_in[3];
    const float* u_h   = (const float*)d_in[4];
    const float* v_x   = (const float*)d_in[5];
    const float* v_h   = (const float*)d_in[6];
    const float* b_x   = (const float*)d_in[7];
    const float* b_h   = (const float*)d_in[8];
    const float* dia_x = (const float*)d_in[9];
    const float* dia_h = (const float*)d_in[10];
    float* out = (float*)d_out;

    char* ws = (char*)d_ws;
    short* P      = (short*)(ws);                                    // 2,097,152 B
    short* uxT    = (short*)(ws + 2097152);                          //    65,536
    short* uhT    = (short*)(ws + 2097152 + 65536);                  //   131,072
    short* Vc     = (short*)(ws + 2097152 + 65536 + 131072);         // 1,048,576
    float* coef_x = (float*)(ws + 2097152 + 65536 + 131072 + 1048576);
    float* coef_h = (float*)(ws + 2097152 + 65536 + 131072 + 1048576 + 8192);

    prep_kernel<<<2456, 256, 0, stream>>>(u_x, u_h, v_x, v_h, uxT, uhT, Vc, coef_x, coef_h);
    stage1_kernel<<<dim3(128, 2), 1024, 0, stream>>>(x, h, uxT, uhT, P);
    stage2_kernel<<<dim3(32, 64), 256, 0, stream>>>(P, Vc, x, h, c,
                                                    coef_x, coef_h, b_x, b_h,
                                                    dia_x, dia_h, out);
}